// Round 7
// baseline (376.209 us; speedup 1.0000x reference)
//
#include <hip/hip_runtime.h>
#include <math.h>

// ETM forward. B=1024 S=512 V=50000 E=300 H=800 T=50.
// k0: zero xbar/topicsum/loss + transpose alpha->aT
// k5: rhoh = bf16(rho) streaming cast
// k4: betaU[v,:] = exp(rho[v,:]@alpha^T) -> bf16 128B rows + topicsum
//     (4 threads/v split e-range, 50 topics in regs, alpha broadcast from LDS)
// k1: token compaction (y=2 halves) + x partial sums from bf16 rho gather
// k2: h=relu(x/n @ W1 + b1)   k3: mu/lv/theta/kl   k6: recon + loss

#define Bn 1024
#define Sn 512
#define Vn 50000
#define En 300
#define Hn 800
#define Tn 50
#define VT4 64             // v per k4 block (4 threads per v)
#define BSTR 64            // betaU bf16 row stride (ushorts) = 128 B

__device__ __forceinline__ float waveReduceSum(float v) {
    #pragma unroll
    for (int off = 32; off > 0; off >>= 1) v += __shfl_xor(v, off, 64);
    return v;
}
__device__ __forceinline__ float waveReduceMax(float v) {
    #pragma unroll
    for (int off = 32; off > 0; off >>= 1) v = fmaxf(v, __shfl_xor(v, off, 64));
    return v;
}
__device__ __forceinline__ unsigned short f2bf(float x) {
    unsigned u = __float_as_uint(x);
    return (unsigned short)((u + 0x7FFFu + ((u >> 16) & 1u)) >> 16);
}
__device__ __forceinline__ float bf_lo(unsigned u) { return __uint_as_float(u << 16); }
__device__ __forceinline__ float bf_hi(unsigned u) { return __uint_as_float(u & 0xFFFF0000u); }

// Zero xbar/topicsum/loss; transpose alpha[t][e] -> aT[e*64 + t].
__global__ __launch_bounds__(256) void k0_init(
        const float* __restrict__ alpha, float* __restrict__ aT,
        float* __restrict__ topicsum, float* __restrict__ loss,
        float* __restrict__ xbar) {
    const int gid = blockIdx.x * 256 + threadIdx.x;
    if (blockIdx.x == 0) {
        if (threadIdx.x < Tn) topicsum[threadIdx.x] = 0.f;
        if (threadIdx.x == 63) *loss = 0.f;
    }
    if (gid < Bn * En) xbar[gid] = 0.f;
    if (gid < Tn * En) {
        int t = gid / En, e = gid - t * En;
        aT[e * 64 + t] = alpha[t * En + e];
    }
}

// Streaming cast rho -> bf16 (coalesced float4 in, ushort4 out).
__global__ __launch_bounds__(256) void k5_cast(
        const float4* __restrict__ rho4, ushort4* __restrict__ rhoh4, int n4) {
    const int i = blockIdx.x * 256 + threadIdx.x;
    if (i < n4) {
        float4 r = rho4[i];
        ushort4 p;
        p.x = f2bf(r.x); p.y = f2bf(r.y); p.z = f2bf(r.z); p.w = f2bf(r.w);
        rhoh4[i] = p;
    }
}

// betaU[v,t] = exp(sum_e rho[v,e]*alpha[t,e]); topicsum[t] += sum_v.
// 64 v per block, 4 threads per v (esec = tid&3 owns float4 idx j = esec+4m:
// lanes 4k..4k+3 read 64B contiguous per row). Alpha staged once in LDS
// ([e][52] 16B rows, broadcast reads). Partial sums merged via shfl_xor(1,2);
// after exp all 4 lanes of a group hold the value, so the xor-4..32 butterfly
// yields EXACTLY the wave's sum over its 16 v (one lane per group per coset).
// Epilogue: LDS transpose (overlaid on asl) -> coalesced dword stores.
__global__ __launch_bounds__(256) void k4_beta(
        const float* __restrict__ rho, const float* __restrict__ aT,
        unsigned int* __restrict__ betaU32, float* __restrict__ topicsum) {
    __shared__ float asl[En * 52];             // 62400 B; reused as trans after loop
    __shared__ float wsum[4][Tn];
    const int tid = threadIdx.x;
    const int v0 = blockIdx.x * VT4;
    const int vl = tid >> 2;                   // 0..63
    const int esec = tid & 3;
    const int v = v0 + vl;
    const bool valid = v < Vn;
    const int vload = valid ? v : (Vn - 1);

    for (int i = tid; i < En * 52; i += 256) {
        int e = i / 52, t = i - e * 52;
        asl[i] = (t < Tn) ? aT[e * 64 + t] : 0.f;
    }
    __syncthreads();

    const float4* rrow = (const float4*)(rho + (size_t)vload * En);  // 75 float4
    float acc[Tn];
    #pragma unroll
    for (int t = 0; t < Tn; ++t) acc[t] = 0.f;

    for (int j = esec; j < 75; j += 4) {
        float4 q = rrow[j];
        float rr[4] = {q.x, q.y, q.z, q.w};
        #pragma unroll
        for (int e = 0; e < 4; ++e) {
            const float* a = &asl[(4 * j + e) * 52];
            float re = rr[e];
            #pragma unroll
            for (int qq = 0; qq < 12; ++qq) {
                float4 av = *(const float4*)(a + 4 * qq);
                acc[4 * qq]     = fmaf(re, av.x, acc[4 * qq]);
                acc[4 * qq + 1] = fmaf(re, av.y, acc[4 * qq + 1]);
                acc[4 * qq + 2] = fmaf(re, av.z, acc[4 * qq + 2]);
                acc[4 * qq + 3] = fmaf(re, av.w, acc[4 * qq + 3]);
            }
            float2 a2 = *(const float2*)(a + 48);
            acc[48] = fmaf(re, a2.x, acc[48]);
            acc[49] = fmaf(re, a2.y, acc[49]);
        }
    }

    // merge the 4 e-sections; exp; butterfly rest for topicsum
    const int wave = tid >> 6, lane = tid & 63;
    #pragma unroll
    for (int t = 0; t < Tn; ++t) {
        float s = acc[t];
        s += __shfl_xor(s, 1, 64);
        s += __shfl_xor(s, 2, 64);
        s = valid ? expf(s) : 0.f;
        acc[t] = s;                 // all 4 lanes of a v hold betaU[v][t]
        s += __shfl_xor(s, 4, 64);
        s += __shfl_xor(s, 8, 64);
        s += __shfl_xor(s, 16, 64);
        s += __shfl_xor(s, 32, 64); // = sum over the wave's 16 v (1 lane/group per coset)
        if (lane == 0) wsum[wave][t] = s;
    }

    __syncthreads();               // asl reads done -> safe to overlay
    unsigned int* trans = (unsigned int*)asl;   // 64 x 33 dwords
    if (esec == 0) {
        #pragma unroll
        for (int i = 0; i < 25; ++i) {
            unsigned pk = (unsigned)f2bf(acc[2 * i]) |
                          ((unsigned)f2bf(acc[2 * i + 1]) << 16);
            trans[vl * 33 + i] = pk;
        }
        #pragma unroll
        for (int i = 25; i < 32; ++i) trans[vl * 33 + i] = 0u;
    }
    __syncthreads();
    if (tid < Tn) {
        atomicAdd(&topicsum[tid],
                  wsum[0][tid] + wsum[1][tid] + wsum[2][tid] + wsum[3][tid]);
    }
    // 64 rows x 32 dwords = 8KB contiguous, coalesced
    unsigned int* dst = betaU32 + (size_t)v0 * 32;
    for (int j = tid; j < VT4 * 32; j += 256) {
        dst[j] = trans[(j >> 5) * 33 + (j & 31)];
    }
}

// Half-doc token compaction + unscaled x partial sums from bf16 rho gather.
// grid (Bn, 2). Lane p<150 owns e-pair (2p, 2p+1): one dword per token.
__global__ __launch_bounds__(256) void k1_tokens_x(
        const int* __restrict__ ids, const unsigned int* __restrict__ rhoh32,
        int* __restrict__ toks, int* __restrict__ cnt2,
        float* __restrict__ xbar) {
    __shared__ int sid[256];
    __shared__ int scount;
    const int b = blockIdx.x, half = blockIdx.y, tid = threadIdx.x;
    if (tid == 0) scount = 0;
    __syncthreads();
    int id = ids[b * Sn + half * 256 + tid];
    if (id != 1 && id != 2) {
        int p = atomicAdd(&scount, 1);
        sid[p] = id;
    }
    __syncthreads();
    const int n = scount;
    if (tid < n) toks[b * Sn + half * 256 + tid] = sid[tid];
    if (tid == 0) cnt2[b * 2 + half] = n;
    if (tid < En / 2) {
        float ax = 0.f, ay = 0.f;
        for (int s = 0; s < n; ++s) {
            unsigned u = rhoh32[sid[s] * (En / 2) + tid];
            ax += bf_lo(u);
            ay += bf_hi(u);
        }
        atomicAdd(&xbar[b * En + 2 * tid], ax);
        atomicAdd(&xbar[b * En + 2 * tid + 1], ay);
    }
}

// h = relu((xsum/n) @ W1 + b1): 8 rows/block; scale folded into staging.
__global__ __launch_bounds__(256) void k2_h(
        const float* __restrict__ xbar, const int* __restrict__ cnt2,
        const float* __restrict__ W1, const float* __restrict__ b1,
        float* __restrict__ h) {
    const int BR = 8;
    __shared__ float xs[BR * En];
    __shared__ float invn[BR];
    const int b0 = blockIdx.x * BR, tid = threadIdx.x;
    if (tid < BR) {
        int bb = b0 + tid;
        invn[tid] = 1.0f / (float)(cnt2[2 * bb] + cnt2[2 * bb + 1]);
    }
    __syncthreads();
    for (int i = tid; i < BR * En; i += 256) xs[i] = xbar[b0 * En + i] * invn[i / En];
    __syncthreads();
    const int j0 = tid, j1 = tid + 256, j2 = tid + 512, j3 = tid + 768;
    const bool has3 = (j3 < Hn);
    float acc[BR][4];
    #pragma unroll
    for (int r = 0; r < BR; ++r) {
        acc[r][0] = b1[j0]; acc[r][1] = b1[j1]; acc[r][2] = b1[j2];
        acc[r][3] = has3 ? b1[j3] : 0.f;
    }
    for (int e = 0; e < En; ++e) {
        float w0 = W1[e * Hn + j0];
        float w1 = W1[e * Hn + j1];
        float w2 = W1[e * Hn + j2];
        float w3 = has3 ? W1[e * Hn + j3] : 0.f;
        #pragma unroll
        for (int r = 0; r < BR; ++r) {
            float xv = xs[r * En + e];
            acc[r][0] += xv * w0; acc[r][1] += xv * w1;
            acc[r][2] += xv * w2; acc[r][3] += xv * w3;
        }
    }
    #pragma unroll
    for (int r = 0; r < BR; ++r) {
        h[(b0 + r) * Hn + j0] = fmaxf(acc[r][0], 0.f);
        h[(b0 + r) * Hn + j1] = fmaxf(acc[r][1], 0.f);
        h[(b0 + r) * Hn + j2] = fmaxf(acc[r][2], 0.f);
        if (has3) h[(b0 + r) * Hn + j3] = fmaxf(acc[r][3], 0.f);
    }
}

// mu/lv = h@Wmu/Wlv + bias; theta = softmax(mu); kl accumulated into loss.
__global__ __launch_bounds__(256) void k3_theta(
        const float* __restrict__ h, const float* __restrict__ Wmu,
        const float* __restrict__ bmu, const float* __restrict__ Wlv,
        const float* __restrict__ blv, float* __restrict__ theta,
        float* __restrict__ loss) {
    const int BR = 16;
    __shared__ float hs[BR * Hn];    // 51.2 KB
    const int b0 = blockIdx.x * BR, tid = threadIdx.x;
    for (int i = tid; i < BR * Hn; i += 256) hs[i] = h[b0 * Hn + i];
    __syncthreads();
    const int wave = tid >> 6, lane = tid & 63;
    const int t = (lane < Tn) ? lane : (Tn - 1);
    const bool act = (lane < Tn);
    float amu[4], alv[4];
    #pragma unroll
    for (int k = 0; k < 4; ++k) { amu[k] = bmu[t]; alv[k] = blv[t]; }
    const int rbase = wave * 4;
    for (int j = 0; j < Hn; ++j) {
        float wm = Wmu[j * Tn + t];
        float wl = Wlv[j * Tn + t];
        #pragma unroll
        for (int k = 0; k < 4; ++k) {
            float hv = hs[(rbase + k) * Hn + j];
            amu[k] += hv * wm;
            alv[k] += hv * wl;
        }
    }
    float klacc = 0.f;
    #pragma unroll
    for (int k = 0; k < 4; ++k) {
        float mu = amu[k], lv = alv[k];
        float m = waveReduceMax(act ? mu : -1e30f);
        float ex = act ? expf(mu - m) : 0.f;
        float ssum = waveReduceSum(ex);
        if (act) theta[(b0 + rbase + k) * Tn + lane] = ex / ssum;
        klacc += waveReduceSum(act ? (1.f + lv - mu * mu - expf(lv)) : 0.f);
    }
    if (lane == 0) atomicAdd(loss, -0.5f * klacc * (1.0f / (float)Bn));
}

// recon[b] = -sum_tok log( sum_t (theta/Z)[t] * betaU[tok,t] + 1e-5 ).
// betaU bf16, 128B rows: one cache line per token; uint4 loads.
__global__ __launch_bounds__(256) void k6_recon(
        const int* __restrict__ toks, const int* __restrict__ cnt2,
        const float* __restrict__ theta, const float* __restrict__ topicsum,
        const unsigned short* __restrict__ betaUh, float* __restrict__ loss) {
    __shared__ float sw[Tn];
    __shared__ float swred[4];
    const int b = blockIdx.x, tid = threadIdx.x;
    if (tid < Tn) sw[tid] = theta[b * Tn + tid] / topicsum[tid];
    __syncthreads();
    float wr[Tn];
    #pragma unroll
    for (int t = 0; t < Tn; ++t) wr[t] = sw[t];
    float lsum = 0.f;
    for (int half = 0; half < 2; ++half) {
        const int n = cnt2[b * 2 + half];
        for (int i = tid; i < n; i += 256) {
            int v = toks[b * Sn + half * 256 + i];
            const uint4* q = (const uint4*)(betaUh + (size_t)v * BSTR);
            float dot = 0.f;
            #pragma unroll
            for (int k = 0; k < 6; ++k) {
                uint4 u = q[k];
                int t = 8 * k;
                dot += wr[t]     * bf_lo(u.x) + wr[t + 1] * bf_hi(u.x);
                dot += wr[t + 2] * bf_lo(u.y) + wr[t + 3] * bf_hi(u.y);
                dot += wr[t + 4] * bf_lo(u.z) + wr[t + 5] * bf_hi(u.z);
                dot += wr[t + 6] * bf_lo(u.w) + wr[t + 7] * bf_hi(u.w);
            }
            unsigned d = ((const unsigned*)q)[24];
            dot += wr[48] * bf_lo(d) + wr[49] * bf_hi(d);
            lsum += logf(dot + 1e-5f);
        }
    }
    float s = waveReduceSum(lsum);
    const int wave = tid >> 6, lane = tid & 63;
    if (lane == 0) swred[wave] = s;
    __syncthreads();
    if (tid == 0) {
        float tot = swred[0] + swred[1] + swred[2] + swred[3];
        atomicAdd(loss, -tot * (1.0f / (float)Bn));
    }
}

extern "C" void kernel_launch(void* const* d_in, const int* in_sizes, int n_in,
                              void* d_out, int out_size, void* d_ws, size_t ws_size,
                              hipStream_t stream) {
    const int*   ids   = (const int*)d_in[0];
    const float* rho   = (const float*)d_in[1];
    const float* alpha = (const float*)d_in[2];
    const float* W1    = (const float*)d_in[3];
    const float* b1    = (const float*)d_in[4];
    const float* Wmu   = (const float*)d_in[5];
    const float* bmu   = (const float*)d_in[6];
    const float* Wlv   = (const float*)d_in[7];
    const float* blv   = (const float*)d_in[8];

    float* theta = (float*)d_out;            // [B, T]
    float* loss  = theta + Bn * Tn;          // scalar at d_out[51200]

    const int k4grid = (Vn + VT4 - 1) / VT4;           // 782
    char* w = (char*)d_ws;
    float* topicsum = (float*)w;               w += 256;
    float* aT       = (float*)w;               w += En * 64 * 4;
    int*   cnt2     = (int*)w;                 w += 2 * Bn * 4;
    int*   toks     = (int*)w;                 w += Bn * Sn * 4;
    float* xbar     = (float*)w;               w += Bn * En * 4;
    float* hbuf     = (float*)w;               w += Bn * Hn * 4;
    unsigned int* rhoh32 = (unsigned int*)w;   w += (size_t)Vn * En * 2;     // 30 MB bf16
    unsigned int* betaU32 = (unsigned int*)w;  w += (size_t)k4grid * VT4 * 128;  // padded rows

    k0_init<<<(Bn * En + 255) / 256, 256, 0, stream>>>(alpha, aT, topicsum, loss, xbar);
    k5_cast<<<(Vn * En / 4 + 255) / 256, 256, 0, stream>>>(
        (const float4*)rho, (ushort4*)rhoh32, Vn * En / 4);
    k4_beta<<<k4grid, 256, 0, stream>>>(rho, aT, betaU32, topicsum);
    k1_tokens_x<<<dim3(Bn, 2), 256, 0, stream>>>(ids, rhoh32, toks, cnt2, xbar);
    k2_h<<<Bn / 8, 256, 0, stream>>>(xbar, cnt2, W1, b1, hbuf);
    k3_theta<<<Bn / 16, 256, 0, stream>>>(hbuf, Wmu, bmu, Wlv, blv, theta, loss);
    k6_recon<<<Bn, 256, 0, stream>>>(toks, cnt2, theta, topicsum,
                                     (const unsigned short*)betaU32, loss);
}

// Round 8
// 302.728 us; speedup vs baseline: 1.2427x; 1.2427x over previous
//
#include <hip/hip_runtime.h>
#include <math.h>

// ETM forward. B=1024 S=512 V=50000 E=300 H=800 T=50.
// k0: zero xbar/topicsum/loss + build MFMA B-fragments from alpha (bf16)
// k5: rhoh = bf16(rho), row-padded to K=320 (zeros)
// k4: betaU = exp(rhoh @ alpha^T) via mfma_f32_16x16x32_bf16 + topicsum
// k1: token compaction (y=2 halves) + x partial sums from bf16 rho gather
// k2: h=relu(x/n @ W1 + b1)   k3: mu/lv/theta/kl   k6: recon + loss

#define Bn 1024
#define Sn 512
#define Vn 50000
#define En 300
#define Hn 800
#define Tn 50
#define KP 320             // padded K (10 tiles of 32)
#define BSTR 64            // betaU bf16 row stride (ushorts) = 128 B

typedef __bf16 bf16x8 __attribute__((ext_vector_type(8)));
typedef float  f32x4  __attribute__((ext_vector_type(4)));

__device__ __forceinline__ float waveReduceSum(float v) {
    #pragma unroll
    for (int off = 32; off > 0; off >>= 1) v += __shfl_xor(v, off, 64);
    return v;
}
__device__ __forceinline__ float waveReduceMax(float v) {
    #pragma unroll
    for (int off = 32; off > 0; off >>= 1) v = fmaxf(v, __shfl_xor(v, off, 64));
    return v;
}
__device__ __forceinline__ unsigned short f2bf(float x) {
    unsigned u = __float_as_uint(x);
    return (unsigned short)((u + 0x7FFFu + ((u >> 16) & 1u)) >> 16);
}
__device__ __forceinline__ float bf_lo(unsigned u) { return __uint_as_float(u << 16); }
__device__ __forceinline__ float bf_hi(unsigned u) { return __uint_as_float(u & 0xFFFF0000u); }

// Zero xbar/topicsum/loss; build B-fragments: bfrag[((w*10+kt)*64+lane)*8+j]
// = bf16(alpha[t= 16w+(lane&15)][e= kt*32+(lane>>4)*8+j]), 0 beyond t/e range.
__global__ __launch_bounds__(256) void k0_init(
        const float* __restrict__ alpha, unsigned short* __restrict__ bfrag,
        float* __restrict__ topicsum, float* __restrict__ loss,
        float* __restrict__ xbar) {
    const int gid = blockIdx.x * 256 + threadIdx.x;
    if (blockIdx.x == 0) {
        if (threadIdx.x < Tn) topicsum[threadIdx.x] = 0.f;
        if (threadIdx.x == 63) *loss = 0.f;
    }
    if (gid < Bn * En) xbar[gid] = 0.f;
    if (gid < 4 * 10 * 64 * 8) {
        int j = gid & 7;
        int lane = (gid >> 3) & 63;
        int rest = gid >> 9;               // w*10 + kt
        int kt = rest % 10, w = rest / 10;
        int t = 16 * w + (lane & 15);
        int e = kt * 32 + (lane >> 4) * 8 + j;
        bfrag[gid] = (t < Tn && e < En) ? f2bf(alpha[t * En + e]) : (unsigned short)0;
    }
}

// Streaming cast rho -> bf16 with row padding to KP (ushort4 slots, 80/row).
__global__ __launch_bounds__(256) void k5_cast(
        const float4* __restrict__ rho4, ushort4* __restrict__ rhoh4) {
    const int i = blockIdx.x * 256 + threadIdx.x;
    if (i < Vn * (KP / 4)) {
        int v = i / (KP / 4), s = i - v * (KP / 4);
        ushort4 p = {0, 0, 0, 0};
        if (s < En / 4) {
            float4 r = rho4[v * (En / 4) + s];
            p.x = f2bf(r.x); p.y = f2bf(r.y); p.z = f2bf(r.z); p.w = f2bf(r.w);
        }
        rhoh4[i] = p;
    }
}

// betaU[v,t] = exp(sum_e rhoh[v,e]*alpha[t,e]) via MFMA; topicsum[t] += sum_v.
// Block = 64 v (4 mtiles of 16); wave w = topic-tile w (t = 16w+lane&15).
// B-frags preloaded (10 x bf16x8); A-frag = 16B load of 8 consecutive bf16.
// D layout: col=lane&15 (t), row=quad*4+reg (v). Epilogue: exp -> bf16 ->
// LDS stride-33 transpose -> coalesced 128B-row stores; topicsum via
// shfl_xor(16,32) (lanes l,l^16,l^32,l^48 share t and cover all 64 v).
__global__ __launch_bounds__(256) void k4_beta(
        const unsigned short* __restrict__ rhoh,
        const unsigned short* __restrict__ bfrag,
        unsigned int* __restrict__ betaU32, float* __restrict__ topicsum) {
    __shared__ unsigned short trans[64 * 66];   // 8448 B (row stride 33 dwords)
    const int tid = threadIdx.x;
    const int wave = tid >> 6, lane = tid & 63;
    const int quad = lane >> 4, l15 = lane & 15;
    const int v0 = blockIdx.x * 64;

    bf16x8 bf[10];
    #pragma unroll
    for (int kt = 0; kt < 10; ++kt)
        bf[kt] = *(const bf16x8*)(bfrag + ((wave * 10 + kt) * 64 + lane) * 8);

    float ts = 0.f;
    #pragma unroll
    for (int mt = 0; mt < 4; ++mt) {
        const int vbase = v0 + mt * 16;
        int vrow = vbase + l15; if (vrow >= Vn) vrow = Vn - 1;
        const unsigned short* arow = rhoh + (size_t)vrow * KP + quad * 8;
        f32x4 acc = {0.f, 0.f, 0.f, 0.f};
        #pragma unroll
        for (int kt = 0; kt < 10; ++kt) {
            bf16x8 a = *(const bf16x8*)(arow + kt * 32);
            acc = __builtin_amdgcn_mfma_f32_16x16x32_bf16(a, bf[kt], acc, 0, 0, 0);
        }
        #pragma unroll
        for (int r = 0; r < 4; ++r) {
            int vv = vbase + quad * 4 + r;
            float ev = (vv < Vn) ? expf(acc[r]) : 0.f;
            ts += ev;
            trans[(mt * 16 + quad * 4 + r) * 66 + 16 * wave + l15] = f2bf(ev);
        }
    }
    ts += __shfl_xor(ts, 16, 64);
    ts += __shfl_xor(ts, 32, 64);
    const int t = 16 * wave + l15;
    if (lane < 16 && t < Tn) atomicAdd(&topicsum[t], ts);
    __syncthreads();
    unsigned int* dst = betaU32 + (size_t)v0 * 32;
    const unsigned int* tr32 = (const unsigned int*)trans;
    for (int i = tid; i < 64 * 32; i += 256)
        dst[i] = tr32[(i >> 5) * 33 + (i & 31)];
}

// Half-doc token compaction + unscaled x partial sums from bf16 rho gather.
// grid (Bn, 2). Lane p<150 owns e-pair (2p, 2p+1); rhoh row stride 160 dwords.
__global__ __launch_bounds__(256) void k1_tokens_x(
        const int* __restrict__ ids, const unsigned int* __restrict__ rhoh32,
        int* __restrict__ toks, int* __restrict__ cnt2,
        float* __restrict__ xbar) {
    __shared__ int sid[256];
    __shared__ int scount;
    const int b = blockIdx.x, half = blockIdx.y, tid = threadIdx.x;
    if (tid == 0) scount = 0;
    __syncthreads();
    int id = ids[b * Sn + half * 256 + tid];
    if (id != 1 && id != 2) {
        int p = atomicAdd(&scount, 1);
        sid[p] = id;
    }
    __syncthreads();
    const int n = scount;
    if (tid < n) toks[b * Sn + half * 256 + tid] = sid[tid];
    if (tid == 0) cnt2[b * 2 + half] = n;
    if (tid < En / 2) {
        float ax = 0.f, ay = 0.f;
        for (int s = 0; s < n; ++s) {
            unsigned u = rhoh32[sid[s] * (KP / 2) + tid];
            ax += bf_lo(u);
            ay += bf_hi(u);
        }
        atomicAdd(&xbar[b * En + 2 * tid], ax);
        atomicAdd(&xbar[b * En + 2 * tid + 1], ay);
    }
}

// h = relu((xsum/n) @ W1 + b1): 8 rows/block; scale folded into staging.
__global__ __launch_bounds__(256) void k2_h(
        const float* __restrict__ xbar, const int* __restrict__ cnt2,
        const float* __restrict__ W1, const float* __restrict__ b1,
        float* __restrict__ h) {
    const int BR = 8;
    __shared__ float xs[BR * En];
    __shared__ float invn[BR];
    const int b0 = blockIdx.x * BR, tid = threadIdx.x;
    if (tid < BR) {
        int bb = b0 + tid;
        invn[tid] = 1.0f / (float)(cnt2[2 * bb] + cnt2[2 * bb + 1]);
    }
    __syncthreads();
    for (int i = tid; i < BR * En; i += 256) xs[i] = xbar[b0 * En + i] * invn[i / En];
    __syncthreads();
    const int j0 = tid, j1 = tid + 256, j2 = tid + 512, j3 = tid + 768;
    const bool has3 = (j3 < Hn);
    float acc[BR][4];
    #pragma unroll
    for (int r = 0; r < BR; ++r) {
        acc[r][0] = b1[j0]; acc[r][1] = b1[j1]; acc[r][2] = b1[j2];
        acc[r][3] = has3 ? b1[j3] : 0.f;
    }
    for (int e = 0; e < En; ++e) {
        float w0 = W1[e * Hn + j0];
        float w1 = W1[e * Hn + j1];
        float w2 = W1[e * Hn + j2];
        float w3 = has3 ? W1[e * Hn + j3] : 0.f;
        #pragma unroll
        for (int r = 0; r < BR; ++r) {
            float xv = xs[r * En + e];
            acc[r][0] += xv * w0; acc[r][1] += xv * w1;
            acc[r][2] += xv * w2; acc[r][3] += xv * w3;
        }
    }
    #pragma unroll
    for (int r = 0; r < BR; ++r) {
        h[(b0 + r) * Hn + j0] = fmaxf(acc[r][0], 0.f);
        h[(b0 + r) * Hn + j1] = fmaxf(acc[r][1], 0.f);
        h[(b0 + r) * Hn + j2] = fmaxf(acc[r][2], 0.f);
        if (has3) h[(b0 + r) * Hn + j3] = fmaxf(acc[r][3], 0.f);
    }
}

// mu/lv = h@Wmu/Wlv + bias; theta = softmax(mu); kl accumulated into loss.
__global__ __launch_bounds__(256) void k3_theta(
        const float* __restrict__ h, const float* __restrict__ Wmu,
        const float* __restrict__ bmu, const float* __restrict__ Wlv,
        const float* __restrict__ blv, float* __restrict__ theta,
        float* __restrict__ loss) {
    const int BR = 16;
    __shared__ float hs[BR * Hn];    // 51.2 KB
    const int b0 = blockIdx.x * BR, tid = threadIdx.x;
    for (int i = tid; i < BR * Hn; i += 256) hs[i] = h[b0 * Hn + i];
    __syncthreads();
    const int wave = tid >> 6, lane = tid & 63;
    const int t = (lane < Tn) ? lane : (Tn - 1);
    const bool act = (lane < Tn);
    float amu[4], alv[4];
    #pragma unroll
    for (int k = 0; k < 4; ++k) { amu[k] = bmu[t]; alv[k] = blv[t]; }
    const int rbase = wave * 4;
    for (int j = 0; j < Hn; ++j) {
        float wm = Wmu[j * Tn + t];
        float wl = Wlv[j * Tn + t];
        #pragma unroll
        for (int k = 0; k < 4; ++k) {
            float hv = hs[(rbase + k) * Hn + j];
            amu[k] += hv * wm;
            alv[k] += hv * wl;
        }
    }
    float klacc = 0.f;
    #pragma unroll
    for (int k = 0; k < 4; ++k) {
        float mu = amu[k], lv = alv[k];
        float m = waveReduceMax(act ? mu : -1e30f);
        float ex = act ? expf(mu - m) : 0.f;
        float ssum = waveReduceSum(ex);
        if (act) theta[(b0 + rbase + k) * Tn + lane] = ex / ssum;
        klacc += waveReduceSum(act ? (1.f + lv - mu * mu - expf(lv)) : 0.f);
    }
    if (lane == 0) atomicAdd(loss, -0.5f * klacc * (1.0f / (float)Bn));
}

// recon[b] = -sum_tok log( sum_t (theta/Z)[t] * betaU[tok,t] + 1e-5 ).
// betaU bf16, 128B rows: one cache line per token; uint4 loads.
__global__ __launch_bounds__(256) void k6_recon(
        const int* __restrict__ toks, const int* __restrict__ cnt2,
        const float* __restrict__ theta, const float* __restrict__ topicsum,
        const unsigned short* __restrict__ betaUh, float* __restrict__ loss) {
    __shared__ float sw[Tn];
    __shared__ float swred[4];
    const int b = blockIdx.x, tid = threadIdx.x;
    if (tid < Tn) sw[tid] = theta[b * Tn + tid] / topicsum[tid];
    __syncthreads();
    float wr[Tn];
    #pragma unroll
    for (int t = 0; t < Tn; ++t) wr[t] = sw[t];
    float lsum = 0.f;
    for (int half = 0; half < 2; ++half) {
        const int n = cnt2[b * 2 + half];
        for (int i = tid; i < n; i += 256) {
            int v = toks[b * Sn + half * 256 + i];
            const uint4* q = (const uint4*)(betaUh + (size_t)v * BSTR);
            float dot = 0.f;
            #pragma unroll
            for (int k = 0; k < 6; ++k) {
                uint4 u = q[k];
                int t = 8 * k;
                dot += wr[t]     * bf_lo(u.x) + wr[t + 1] * bf_hi(u.x);
                dot += wr[t + 2] * bf_lo(u.y) + wr[t + 3] * bf_hi(u.y);
                dot += wr[t + 4] * bf_lo(u.z) + wr[t + 5] * bf_hi(u.z);
                dot += wr[t + 6] * bf_lo(u.w) + wr[t + 7] * bf_hi(u.w);
            }
            unsigned d = ((const unsigned*)q)[24];
            dot += wr[48] * bf_lo(d) + wr[49] * bf_hi(d);
            lsum += logf(dot + 1e-5f);
        }
    }
    float s = waveReduceSum(lsum);
    const int wave = tid >> 6, lane = tid & 63;
    if (lane == 0) swred[wave] = s;
    __syncthreads();
    if (tid == 0) {
        float tot = swred[0] + swred[1] + swred[2] + swred[3];
        atomicAdd(loss, -tot * (1.0f / (float)Bn));
    }
}

extern "C" void kernel_launch(void* const* d_in, const int* in_sizes, int n_in,
                              void* d_out, int out_size, void* d_ws, size_t ws_size,
                              hipStream_t stream) {
    const int*   ids   = (const int*)d_in[0];
    const float* rho   = (const float*)d_in[1];
    const float* alpha = (const float*)d_in[2];
    const float* W1    = (const float*)d_in[3];
    const float* b1    = (const float*)d_in[4];
    const float* Wmu   = (const float*)d_in[5];
    const float* bmu   = (const float*)d_in[6];
    const float* Wlv   = (const float*)d_in[7];
    const float* blv   = (const float*)d_in[8];

    float* theta = (float*)d_out;            // [B, T]
    float* loss  = theta + Bn * Tn;          // scalar at d_out[51200]

    const int k4grid = (Vn + 63) / 64;                  // 782
    char* w = (char*)d_ws;
    float* topicsum = (float*)w;                w += 256;
    unsigned short* bfrag = (unsigned short*)w; w += 4 * 10 * 64 * 8 * 2;   // 40960 B
    int*   cnt2     = (int*)w;                  w += 2 * Bn * 4;
    int*   toks     = (int*)w;                  w += Bn * Sn * 4;
    float* xbar     = (float*)w;                w += Bn * En * 4;
    float* hbuf     = (float*)w;                w += Bn * Hn * 4;
    unsigned short* rhoh = (unsigned short*)w;  w += (size_t)Vn * KP * 2;   // 32 MB padded
    unsigned int* betaU32 = (unsigned int*)w;   w += (size_t)k4grid * 64 * 128;

    k0_init<<<(Bn * En + 255) / 256, 256, 0, stream>>>(alpha, bfrag, topicsum, loss, xbar);
    k5_cast<<<(Vn * (KP / 4) + 255) / 256, 256, 0, stream>>>(
        (const float4*)rho, (ushort4*)rhoh);
    k4_beta<<<k4grid, 256, 0, stream>>>(rhoh, bfrag, betaU32, topicsum);
    k1_tokens_x<<<dim3(Bn, 2), 256, 0, stream>>>(ids, (const unsigned int*)rhoh, toks, cnt2, xbar);
    k2_h<<<Bn / 8, 256, 0, stream>>>(xbar, cnt2, W1, b1, hbuf);
    k3_theta<<<Bn / 16, 256, 0, stream>>>(hbuf, Wmu, bmu, Wlv, blv, theta, loss);
    k6_recon<<<Bn, 256, 0, stream>>>(toks, cnt2, theta, topicsum,
                                     (const unsigned short*)betaU32, loss);
}

// Round 9
// 231.898 us; speedup vs baseline: 1.6223x; 1.3054x over previous
//
#include <hip/hip_runtime.h>
#include <math.h>

// ETM forward. B=1024 S=512 V=50000 E=300 H=800 T=50.
// k0: zero xbar/topicsum/loss + alpha MFMA B-frags
// kp: W1 / [Wmu|Wlv] MFMA B-frags (bf16)
// k5: rhoh = bf16(rho), row-padded to K=320
// k4: betaU = exp(rhoh @ alpha^T) via MFMA + topicsum
// k1: token compaction + x partial sums (bf16 rho gather)
// k2a: xbh = bf16(xbar/n) padded K=320
// k2: hbh = bf16(relu(x@W1+b1)) via MFMA
// k3: mu/lv via MFMA -> LDS -> softmax/theta/kl
// k6: recon + loss

#define Bn 1024
#define Sn 512
#define Vn 50000
#define En 300
#define Hn 800
#define Tn 50
#define KP 320             // padded K for E-dim (10 tiles of 32)
#define BSTR 64            // betaU bf16 row stride (ushorts) = 128 B
#define W1FRAG_N (50 * 10 * 64 * 8)
#define WFRAG_N  (8 * 25 * 64 * 8)

typedef __bf16 bf16x8 __attribute__((ext_vector_type(8)));
typedef float  f32x4  __attribute__((ext_vector_type(4)));

__device__ __forceinline__ float waveReduceSum(float v) {
    #pragma unroll
    for (int off = 32; off > 0; off >>= 1) v += __shfl_xor(v, off, 64);
    return v;
}
__device__ __forceinline__ float waveReduceMax(float v) {
    #pragma unroll
    for (int off = 32; off > 0; off >>= 1) v = fmaxf(v, __shfl_xor(v, off, 64));
    return v;
}
__device__ __forceinline__ unsigned short f2bf(float x) {
    unsigned u = __float_as_uint(x);
    return (unsigned short)((u + 0x7FFFu + ((u >> 16) & 1u)) >> 16);
}
__device__ __forceinline__ float bf_lo(unsigned u) { return __uint_as_float(u << 16); }
__device__ __forceinline__ float bf_hi(unsigned u) { return __uint_as_float(u & 0xFFFF0000u); }

// Zero xbar/topicsum/loss; alpha B-frags: bfrag[((w*10+kt)*64+lane)*8+j]
// = bf16(alpha[t=16w+(lane&15)][e=kt*32+(lane>>4)*8+j]), 0 outside range.
__global__ __launch_bounds__(256) void k0_init(
        const float* __restrict__ alpha, unsigned short* __restrict__ bfrag,
        float* __restrict__ topicsum, float* __restrict__ loss,
        float* __restrict__ xbar) {
    const int gid = blockIdx.x * 256 + threadIdx.x;
    if (blockIdx.x == 0) {
        if (threadIdx.x < Tn) topicsum[threadIdx.x] = 0.f;
        if (threadIdx.x == 63) *loss = 0.f;
    }
    if (gid < Bn * En) xbar[gid] = 0.f;
    if (gid < 4 * 10 * 64 * 8) {
        int j = gid & 7;
        int lane = (gid >> 3) & 63;
        int rest = gid >> 9;               // w*10 + kt
        int kt = rest % 10, w = rest / 10;
        int t = 16 * w + (lane & 15);
        int e = kt * 32 + (lane >> 4) * 8 + j;
        bfrag[gid] = (t < Tn && e < En) ? f2bf(alpha[t * En + e]) : (unsigned short)0;
    }
}

// B-frags for W1 (50 nt x 10 kt) and [Wmu|Wlv] (8 nt x 25 kt, t>=50 zero).
__global__ __launch_bounds__(256) void kp_prep(
        const float* __restrict__ W1, const float* __restrict__ Wmu,
        const float* __restrict__ Wlv, unsigned short* __restrict__ w1frag,
        unsigned short* __restrict__ wfrag) {
    const int gid = blockIdx.x * 256 + threadIdx.x;
    if (gid < W1FRAG_N) {
        int j = gid & 7, lane = (gid >> 3) & 63, rest = gid >> 9;
        int kt = rest % 10, nt = rest / 10;
        int e = kt * 32 + (lane >> 4) * 8 + j;
        int hcol = nt * 16 + (lane & 15);
        w1frag[gid] = (e < En) ? f2bf(W1[e * Hn + hcol]) : (unsigned short)0;
    } else {
        int g2 = gid - W1FRAG_N;
        if (g2 < WFRAG_N) {
            int j = g2 & 7, lane = (g2 >> 3) & 63, rest = g2 >> 9;
            int kt = rest % 25, nt = rest / 25;
            int k = kt * 32 + (lane >> 4) * 8 + j;        // < 800 always
            int t = (nt & 3) * 16 + (lane & 15);
            float val = 0.f;
            if (t < Tn) val = (nt < 4) ? Wmu[k * Tn + t] : Wlv[k * Tn + t];
            wfrag[g2] = f2bf(val);
        }
    }
}

// Streaming cast rho -> bf16 with row padding to KP.
__global__ __launch_bounds__(256) void k5_cast(
        const float4* __restrict__ rho4, ushort4* __restrict__ rhoh4) {
    const int i = blockIdx.x * 256 + threadIdx.x;
    if (i < Vn * (KP / 4)) {
        int v = i / (KP / 4), s = i - v * (KP / 4);
        ushort4 p = {0, 0, 0, 0};
        if (s < En / 4) {
            float4 r = rho4[v * (En / 4) + s];
            p.x = f2bf(r.x); p.y = f2bf(r.y); p.z = f2bf(r.z); p.w = f2bf(r.w);
        }
        rhoh4[i] = p;
    }
}

// betaU = exp(rhoh @ alpha^T) via MFMA; topicsum[t] += sum_v. (R8, known-good)
__global__ __launch_bounds__(256) void k4_beta(
        const unsigned short* __restrict__ rhoh,
        const unsigned short* __restrict__ bfrag,
        unsigned int* __restrict__ betaU32, float* __restrict__ topicsum) {
    __shared__ unsigned short trans[64 * 66];
    const int tid = threadIdx.x;
    const int wave = tid >> 6, lane = tid & 63;
    const int quad = lane >> 4, l15 = lane & 15;
    const int v0 = blockIdx.x * 64;

    bf16x8 bf[10];
    #pragma unroll
    for (int kt = 0; kt < 10; ++kt)
        bf[kt] = *(const bf16x8*)(bfrag + ((wave * 10 + kt) * 64 + lane) * 8);

    float ts = 0.f;
    #pragma unroll
    for (int mt = 0; mt < 4; ++mt) {
        const int vbase = v0 + mt * 16;
        int vrow = vbase + l15; if (vrow >= Vn) vrow = Vn - 1;
        const unsigned short* arow = rhoh + (size_t)vrow * KP + quad * 8;
        f32x4 acc = {0.f, 0.f, 0.f, 0.f};
        #pragma unroll
        for (int kt = 0; kt < 10; ++kt) {
            bf16x8 a = *(const bf16x8*)(arow + kt * 32);
            acc = __builtin_amdgcn_mfma_f32_16x16x32_bf16(a, bf[kt], acc, 0, 0, 0);
        }
        #pragma unroll
        for (int r = 0; r < 4; ++r) {
            int vv = vbase + quad * 4 + r;
            float ev = (vv < Vn) ? expf(acc[r]) : 0.f;
            ts += ev;
            trans[(mt * 16 + quad * 4 + r) * 66 + 16 * wave + l15] = f2bf(ev);
        }
    }
    ts += __shfl_xor(ts, 16, 64);
    ts += __shfl_xor(ts, 32, 64);
    const int t = 16 * wave + l15;
    if (lane < 16 && t < Tn) atomicAdd(&topicsum[t], ts);
    __syncthreads();
    unsigned int* dst = betaU32 + (size_t)v0 * 32;
    const unsigned int* tr32 = (const unsigned int*)trans;
    for (int i = tid; i < 64 * 32; i += 256)
        dst[i] = tr32[(i >> 5) * 33 + (i & 31)];
}

// Half-doc token compaction + unscaled x partial sums (bf16 rho gather).
__global__ __launch_bounds__(256) void k1_tokens_x(
        const int* __restrict__ ids, const unsigned int* __restrict__ rhoh32,
        int* __restrict__ toks, int* __restrict__ cnt2,
        float* __restrict__ xbar) {
    __shared__ int sid[256];
    __shared__ int scount;
    const int b = blockIdx.x, half = blockIdx.y, tid = threadIdx.x;
    if (tid == 0) scount = 0;
    __syncthreads();
    int id = ids[b * Sn + half * 256 + tid];
    if (id != 1 && id != 2) {
        int p = atomicAdd(&scount, 1);
        sid[p] = id;
    }
    __syncthreads();
    const int n = scount;
    if (tid < n) toks[b * Sn + half * 256 + tid] = sid[tid];
    if (tid == 0) cnt2[b * 2 + half] = n;
    if (tid < En / 2) {
        float ax = 0.f, ay = 0.f;
        for (int s = 0; s < n; ++s) {
            unsigned u = rhoh32[sid[s] * (KP / 2) + tid];
            ax += bf_lo(u);
            ay += bf_hi(u);
        }
        atomicAdd(&xbar[b * En + 2 * tid], ax);
        atomicAdd(&xbar[b * En + 2 * tid + 1], ay);
    }
}

// xbh[b][e<320] = bf16(xbar[b][e]/n_b), zero pad e>=300.
__global__ __launch_bounds__(256) void k2a_xcast(
        const float* __restrict__ xbar, const int* __restrict__ cnt2,
        unsigned short* __restrict__ xbh) {
    const int gid = blockIdx.x * 256 + threadIdx.x;
    if (gid < Bn * KP) {
        int b = gid / KP, e = gid - b * KP;
        unsigned short out = 0;
        if (e < En) {
            float invn = 1.0f / (float)(cnt2[2 * b] + cnt2[2 * b + 1]);
            out = f2bf(xbar[b * En + e] * invn);
        }
        xbh[gid] = out;
    }
}

// hbh = bf16(relu(x@W1+b1)) via MFMA. grid (64 mtiles, 13 nt-groups);
// wave = one ntile (16 h-cols). D: col=l15, row=quad*4+r.
__global__ __launch_bounds__(256) void k2_h(
        const unsigned short* __restrict__ xbh,
        const unsigned short* __restrict__ w1frag,
        const float* __restrict__ b1, unsigned short* __restrict__ hbh) {
    const int tid = threadIdx.x;
    const int wave = tid >> 6, lane = tid & 63;
    const int quad = lane >> 4, l15 = lane & 15;
    const int b0 = blockIdx.x * 16;
    const int nt = blockIdx.y * 4 + wave;
    if (nt >= 50) return;                  // wave-uniform
    const unsigned short* arow = xbh + (size_t)(b0 + l15) * KP + quad * 8;
    f32x4 acc = {0.f, 0.f, 0.f, 0.f};
    #pragma unroll
    for (int kt = 0; kt < 10; ++kt) {
        bf16x8 a = *(const bf16x8*)(arow + kt * 32);
        bf16x8 bv = *(const bf16x8*)(w1frag + ((size_t)(nt * 10 + kt) * 64 + lane) * 8);
        acc = __builtin_amdgcn_mfma_f32_16x16x32_bf16(a, bv, acc, 0, 0, 0);
    }
    const int col = nt * 16 + l15;
    const float bias = b1[col];
    #pragma unroll
    for (int r = 0; r < 4; ++r) {
        int row = b0 + quad * 4 + r;
        hbh[(size_t)row * Hn + col] = f2bf(fmaxf(acc[r] + bias, 0.f));
    }
}

// mu/lv = h@[Wmu|Wlv]+bias via MFMA (wave w: mu-ntile w + lv-ntile w),
// D+bias -> LDS (stride 65) -> per-wave softmax/theta/kl epilogue.
__global__ __launch_bounds__(256) void k3_theta(
        const unsigned short* __restrict__ hbh,
        const unsigned short* __restrict__ wfrag,
        const float* __restrict__ bmu, const float* __restrict__ blv,
        float* __restrict__ theta, float* __restrict__ loss) {
    __shared__ float mlds[16 * 65];
    __shared__ float llds[16 * 65];
    const int tid = threadIdx.x;
    const int wave = tid >> 6, lane = tid & 63;
    const int quad = lane >> 4, l15 = lane & 15;
    const int b0 = blockIdx.x * 16;
    const unsigned short* arow = hbh + (size_t)(b0 + l15) * Hn + quad * 8;
    f32x4 am = {0.f, 0.f, 0.f, 0.f}, al = {0.f, 0.f, 0.f, 0.f};
    #pragma unroll
    for (int kt = 0; kt < 25; ++kt) {
        bf16x8 a  = *(const bf16x8*)(arow + kt * 32);
        bf16x8 bm = *(const bf16x8*)(wfrag + ((size_t)(wave * 25 + kt) * 64 + lane) * 8);
        bf16x8 bl = *(const bf16x8*)(wfrag + ((size_t)((4 + wave) * 25 + kt) * 64 + lane) * 8);
        am = __builtin_amdgcn_mfma_f32_16x16x32_bf16(a, bm, am, 0, 0, 0);
        al = __builtin_amdgcn_mfma_f32_16x16x32_bf16(a, bl, al, 0, 0, 0);
    }
    const int t = wave * 16 + l15;                 // 0..63 LDS col
    const float bm_ = (t < Tn) ? bmu[t] : 0.f;
    const float bl_ = (t < Tn) ? blv[t] : 0.f;
    #pragma unroll
    for (int r = 0; r < 4; ++r) {
        int row = quad * 4 + r;
        mlds[row * 65 + t] = am[r] + bm_;
        llds[row * 65 + t] = al[r] + bl_;
    }
    __syncthreads();
    const int tt = (lane < Tn) ? lane : (Tn - 1);
    const bool act = (lane < Tn);
    float klacc = 0.f;
    #pragma unroll
    for (int k = 0; k < 4; ++k) {
        int row = wave * 4 + k;
        float mu = mlds[row * 65 + tt];
        float lv = llds[row * 65 + tt];
        float m = waveReduceMax(act ? mu : -1e30f);
        float ex = act ? expf(mu - m) : 0.f;
        float ssum = waveReduceSum(ex);
        if (act) theta[(b0 + row) * Tn + lane] = ex / ssum;
        klacc += waveReduceSum(act ? (1.f + lv - mu * mu - expf(lv)) : 0.f);
    }
    if (lane == 0) atomicAdd(loss, -0.5f * klacc * (1.0f / (float)Bn));
}

// recon[b] = -sum_tok log( sum_t (theta/Z)[t] * betaU[tok,t] + 1e-5 ).
__global__ __launch_bounds__(256) void k6_recon(
        const int* __restrict__ toks, const int* __restrict__ cnt2,
        const float* __restrict__ theta, const float* __restrict__ topicsum,
        const unsigned short* __restrict__ betaUh, float* __restrict__ loss) {
    __shared__ float sw[Tn];
    __shared__ float swred[4];
    const int b = blockIdx.x, tid = threadIdx.x;
    if (tid < Tn) sw[tid] = theta[b * Tn + tid] / topicsum[tid];
    __syncthreads();
    float wr[Tn];
    #pragma unroll
    for (int t = 0; t < Tn; ++t) wr[t] = sw[t];
    float lsum = 0.f;
    for (int half = 0; half < 2; ++half) {
        const int n = cnt2[b * 2 + half];
        for (int i = tid; i < n; i += 256) {
            int v = toks[b * Sn + half * 256 + i];
            const uint4* q = (const uint4*)(betaUh + (size_t)v * BSTR);
            float dot = 0.f;
            #pragma unroll
            for (int k = 0; k < 6; ++k) {
                uint4 u = q[k];
                int t = 8 * k;
                dot += wr[t]     * bf_lo(u.x) + wr[t + 1] * bf_hi(u.x);
                dot += wr[t + 2] * bf_lo(u.y) + wr[t + 3] * bf_hi(u.y);
                dot += wr[t + 4] * bf_lo(u.z) + wr[t + 5] * bf_hi(u.z);
                dot += wr[t + 6] * bf_lo(u.w) + wr[t + 7] * bf_hi(u.w);
            }
            unsigned d = ((const unsigned*)q)[24];
            dot += wr[48] * bf_lo(d) + wr[49] * bf_hi(d);
            lsum += logf(dot + 1e-5f);
        }
    }
    float s = waveReduceSum(lsum);
    const int wave = tid >> 6, lane = tid & 63;
    if (lane == 0) swred[wave] = s;
    __syncthreads();
    if (tid == 0) {
        float tot = swred[0] + swred[1] + swred[2] + swred[3];
        atomicAdd(loss, -tot * (1.0f / (float)Bn));
    }
}

extern "C" void kernel_launch(void* const* d_in, const int* in_sizes, int n_in,
                              void* d_out, int out_size, void* d_ws, size_t ws_size,
                              hipStream_t stream) {
    const int*   ids   = (const int*)d_in[0];
    const float* rho   = (const float*)d_in[1];
    const float* alpha = (const float*)d_in[2];
    const float* W1    = (const float*)d_in[3];
    const float* b1    = (const float*)d_in[4];
    const float* Wmu   = (const float*)d_in[5];
    const float* bmu   = (const float*)d_in[6];
    const float* Wlv   = (const float*)d_in[7];
    const float* blv   = (const float*)d_in[8];

    float* theta = (float*)d_out;            // [B, T]
    float* loss  = theta + Bn * Tn;          // scalar at d_out[51200]

    const int k4grid = (Vn + 63) / 64;                  // 782
    char* w = (char*)d_ws;
    float* topicsum = (float*)w;                w += 256;
    unsigned short* bfrag = (unsigned short*)w; w += 4 * 10 * 64 * 8 * 2;
    unsigned short* w1frag = (unsigned short*)w; w += (size_t)W1FRAG_N * 2;
    unsigned short* wfrag = (unsigned short*)w;  w += (size_t)WFRAG_N * 2;
    int*   cnt2     = (int*)w;                  w += 2 * Bn * 4;
    int*   toks     = (int*)w;                  w += Bn * Sn * 4;
    float* xbar     = (float*)w;                w += Bn * En * 4;
    unsigned short* xbh = (unsigned short*)w;   w += (size_t)Bn * KP * 2;
    unsigned short* hbh = (unsigned short*)w;   w += (size_t)Bn * Hn * 2;
    unsigned short* rhoh = (unsigned short*)w;  w += (size_t)Vn * KP * 2;   // 32 MB
    unsigned int* betaU32 = (unsigned int*)w;   w += (size_t)k4grid * 64 * 128;

    k0_init<<<(Bn * En + 255) / 256, 256, 0, stream>>>(alpha, bfrag, topicsum, loss, xbar);
    kp_prep<<<(W1FRAG_N + WFRAG_N + 255) / 256, 256, 0, stream>>>(
        W1, Wmu, Wlv, w1frag, wfrag);
    k5_cast<<<(Vn * (KP / 4) + 255) / 256, 256, 0, stream>>>(
        (const float4*)rho, (ushort4*)rhoh);
    k4_beta<<<k4grid, 256, 0, stream>>>(rhoh, bfrag, betaU32, topicsum);
    k1_tokens_x<<<dim3(Bn, 2), 256, 0, stream>>>(ids, (const unsigned int*)rhoh, toks, cnt2, xbar);
    k2a_xcast<<<(Bn * KP + 255) / 256, 256, 0, stream>>>(xbar, cnt2, xbh);
    k2_h<<<dim3(64, 13), 256, 0, stream>>>(xbh, w1frag, b1, hbh);
    k3_theta<<<64, 256, 0, stream>>>(hbh, wfrag, bmu, blv, theta, loss);
    k6_recon<<<Bn, 256, 0, stream>>>(toks, cnt2, theta, topicsum,
                                     (const unsigned short*)betaU32, loss);
}

// Round 10
// 224.332 us; speedup vs baseline: 1.6770x; 1.0337x over previous
//
#include <hip/hip_runtime.h>
#include <math.h>

// ETM forward. B=1024 S=512 V=50000 E=300 H=800 T=50.
// k0: zero xbar/topicsum/loss + alpha MFMA B-frags
// kp: W1 / [Wmu|Wlv] MFMA B-frags (bf16)
// k5: rhoh = bf16(rho), row-padded to K=320
// k4: betaU = exp(rhoh @ alpha^T) via MFMA + topicsum
// k1: vocab-range-sliced token gather (8 ranges -> per-XCD L2 residency)
// k2a: xbh = bf16(xbar/n) padded K=320
// k2: hbh = bf16(relu(x@W1+b1)) via MFMA
// k3: mu/lv via MFMA -> LDS -> softmax/theta/kl
// k6: recon + loss

#define Bn 1024
#define Sn 512
#define Vn 50000
#define En 300
#define Hn 800
#define Tn 50
#define KP 320             // padded K for E-dim (10 tiles of 32)
#define BSTR 64            // betaU bf16 row stride (ushorts) = 128 B
#define W1FRAG_N (50 * 10 * 64 * 8)
#define WFRAG_N  (8 * 25 * 64 * 8)
#define NRANGE 8
#define VRANGE (Vn / NRANGE)   // 6250 words = 3.8 MB rhoh slice (fits 4MB L2)

typedef __bf16 bf16x8 __attribute__((ext_vector_type(8)));
typedef float  f32x4  __attribute__((ext_vector_type(4)));

__device__ __forceinline__ float waveReduceSum(float v) {
    #pragma unroll
    for (int off = 32; off > 0; off >>= 1) v += __shfl_xor(v, off, 64);
    return v;
}
__device__ __forceinline__ float waveReduceMax(float v) {
    #pragma unroll
    for (int off = 32; off > 0; off >>= 1) v = fmaxf(v, __shfl_xor(v, off, 64));
    return v;
}
__device__ __forceinline__ unsigned short f2bf(float x) {
    unsigned u = __float_as_uint(x);
    return (unsigned short)((u + 0x7FFFu + ((u >> 16) & 1u)) >> 16);
}
__device__ __forceinline__ float bf_lo(unsigned u) { return __uint_as_float(u << 16); }
__device__ __forceinline__ float bf_hi(unsigned u) { return __uint_as_float(u & 0xFFFF0000u); }

// Zero xbar/topicsum/loss; alpha B-frags (MFMA B layout).
__global__ __launch_bounds__(256) void k0_init(
        const float* __restrict__ alpha, unsigned short* __restrict__ bfrag,
        float* __restrict__ topicsum, float* __restrict__ loss,
        float* __restrict__ xbar) {
    const int gid = blockIdx.x * 256 + threadIdx.x;
    if (blockIdx.x == 0) {
        if (threadIdx.x < Tn) topicsum[threadIdx.x] = 0.f;
        if (threadIdx.x == 63) *loss = 0.f;
    }
    if (gid < Bn * En) xbar[gid] = 0.f;
    if (gid < 4 * 10 * 64 * 8) {
        int j = gid & 7;
        int lane = (gid >> 3) & 63;
        int rest = gid >> 9;               // w*10 + kt
        int kt = rest % 10, w = rest / 10;
        int t = 16 * w + (lane & 15);
        int e = kt * 32 + (lane >> 4) * 8 + j;
        bfrag[gid] = (t < Tn && e < En) ? f2bf(alpha[t * En + e]) : (unsigned short)0;
    }
}

// B-frags for W1 (50 nt x 10 kt) and [Wmu|Wlv] (8 nt x 25 kt, t>=50 zero).
__global__ __launch_bounds__(256) void kp_prep(
        const float* __restrict__ W1, const float* __restrict__ Wmu,
        const float* __restrict__ Wlv, unsigned short* __restrict__ w1frag,
        unsigned short* __restrict__ wfrag) {
    const int gid = blockIdx.x * 256 + threadIdx.x;
    if (gid < W1FRAG_N) {
        int j = gid & 7, lane = (gid >> 3) & 63, rest = gid >> 9;
        int kt = rest % 10, nt = rest / 10;
        int e = kt * 32 + (lane >> 4) * 8 + j;
        int hcol = nt * 16 + (lane & 15);
        w1frag[gid] = (e < En) ? f2bf(W1[e * Hn + hcol]) : (unsigned short)0;
    } else {
        int g2 = gid - W1FRAG_N;
        if (g2 < WFRAG_N) {
            int j = g2 & 7, lane = (g2 >> 3) & 63, rest = g2 >> 9;
            int kt = rest % 25, nt = rest / 25;
            int k = kt * 32 + (lane >> 4) * 8 + j;        // < 800 always
            int t = (nt & 3) * 16 + (lane & 15);
            float val = 0.f;
            if (t < Tn) val = (nt < 4) ? Wmu[k * Tn + t] : Wlv[k * Tn + t];
            wfrag[g2] = f2bf(val);
        }
    }
}

// Streaming cast rho -> bf16 with row padding to KP.
__global__ __launch_bounds__(256) void k5_cast(
        const float4* __restrict__ rho4, ushort4* __restrict__ rhoh4) {
    const int i = blockIdx.x * 256 + threadIdx.x;
    if (i < Vn * (KP / 4)) {
        int v = i / (KP / 4), s = i - v * (KP / 4);
        ushort4 p = {0, 0, 0, 0};
        if (s < En / 4) {
            float4 r = rho4[v * (En / 4) + s];
            p.x = f2bf(r.x); p.y = f2bf(r.y); p.z = f2bf(r.z); p.w = f2bf(r.w);
        }
        rhoh4[i] = p;
    }
}

// betaU = exp(rhoh @ alpha^T) via MFMA; topicsum[t] += sum_v. (known-good)
__global__ __launch_bounds__(256) void k4_beta(
        const unsigned short* __restrict__ rhoh,
        const unsigned short* __restrict__ bfrag,
        unsigned int* __restrict__ betaU32, float* __restrict__ topicsum) {
    __shared__ unsigned short trans[64 * 66];
    const int tid = threadIdx.x;
    const int wave = tid >> 6, lane = tid & 63;
    const int quad = lane >> 4, l15 = lane & 15;
    const int v0 = blockIdx.x * 64;

    bf16x8 bf[10];
    #pragma unroll
    for (int kt = 0; kt < 10; ++kt)
        bf[kt] = *(const bf16x8*)(bfrag + ((wave * 10 + kt) * 64 + lane) * 8);

    float ts = 0.f;
    #pragma unroll
    for (int mt = 0; mt < 4; ++mt) {
        const int vbase = v0 + mt * 16;
        int vrow = vbase + l15; if (vrow >= Vn) vrow = Vn - 1;
        const unsigned short* arow = rhoh + (size_t)vrow * KP + quad * 8;
        f32x4 acc = {0.f, 0.f, 0.f, 0.f};
        #pragma unroll
        for (int kt = 0; kt < 10; ++kt) {
            bf16x8 a = *(const bf16x8*)(arow + kt * 32);
            acc = __builtin_amdgcn_mfma_f32_16x16x32_bf16(a, bf[kt], acc, 0, 0, 0);
        }
        #pragma unroll
        for (int r = 0; r < 4; ++r) {
            int vv = vbase + quad * 4 + r;
            float ev = (vv < Vn) ? expf(acc[r]) : 0.f;
            ts += ev;
            trans[(mt * 16 + quad * 4 + r) * 66 + 16 * wave + l15] = f2bf(ev);
        }
    }
    ts += __shfl_xor(ts, 16, 64);
    ts += __shfl_xor(ts, 32, 64);
    const int t = 16 * wave + l15;
    if (lane < 16 && t < Tn) atomicAdd(&topicsum[t], ts);
    __syncthreads();
    unsigned int* dst = betaU32 + (size_t)v0 * 32;
    const unsigned int* tr32 = (const unsigned int*)trans;
    for (int i = tid; i < 64 * 32; i += 256)
        dst[i] = tr32[(i >> 5) * 33 + (i & 31)];
}

// Vocab-range-sliced gather: blk = b*8 + r processes doc b's tokens with
// id in [r*6250,(r+1)*6250) -> each XCD's L2 holds one 3.8MB rhoh slice
// (round-robin dispatch heuristic; correctness mapping-independent).
// r==0 block also writes the full compacted token list + count for k6.
__global__ __launch_bounds__(256) void k1_tokens_x(
        const int* __restrict__ ids, const unsigned int* __restrict__ rhoh32,
        int* __restrict__ toks, int* __restrict__ cnt,
        float* __restrict__ xbar) {
    __shared__ int sid[Sn];        // range-filtered tokens
    __shared__ int sfid[Sn];       // full compaction (r==0 only)
    __shared__ int scount, sfull;
    const int blk = blockIdx.x;
    const int r = blk & (NRANGE - 1), b = blk >> 3;
    const int tid = threadIdx.x;
    const int lo = r * VRANGE, hi = lo + VRANGE;
    if (tid == 0) { scount = 0; sfull = 0; }
    __syncthreads();
    #pragma unroll
    for (int s0 = 0; s0 < Sn; s0 += 256) {
        int id = ids[b * Sn + s0 + tid];
        bool val = (id != 1 && id != 2);
        if (val && id >= lo && id < hi) {
            int p = atomicAdd(&scount, 1);
            sid[p] = id;
        }
        if (r == 0 && val) {
            int p = atomicAdd(&sfull, 1);
            sfid[p] = id;
        }
    }
    __syncthreads();
    if (r == 0) {
        const int nf = sfull;
        for (int i = tid; i < nf; i += 256) toks[b * Sn + i] = sfid[i];
        if (tid == 0) cnt[b] = nf;
    }
    const int m = scount;
    if (tid < En / 2) {
        float ax = 0.f, ay = 0.f;
        for (int s = 0; s < m; ++s) {
            unsigned u = rhoh32[sid[s] * (KP / 2) + tid];
            ax += bf_lo(u);
            ay += bf_hi(u);
        }
        if (m > 0) {
            atomicAdd(&xbar[b * En + 2 * tid], ax);
            atomicAdd(&xbar[b * En + 2 * tid + 1], ay);
        }
    }
}

// xbh[b][e<320] = bf16(xbar[b][e]/n_b), zero pad e>=300.
__global__ __launch_bounds__(256) void k2a_xcast(
        const float* __restrict__ xbar, const int* __restrict__ cnt,
        unsigned short* __restrict__ xbh) {
    const int gid = blockIdx.x * 256 + threadIdx.x;
    if (gid < Bn * KP) {
        int b = gid / KP, e = gid - b * KP;
        unsigned short out = 0;
        if (e < En) {
            float invn = 1.0f / (float)cnt[b];
            out = f2bf(xbar[b * En + e] * invn);
        }
        xbh[gid] = out;
    }
}

// hbh = bf16(relu(x@W1+b1)) via MFMA. grid (64 mtiles, 13 nt-groups).
__global__ __launch_bounds__(256) void k2_h(
        const unsigned short* __restrict__ xbh,
        const unsigned short* __restrict__ w1frag,
        const float* __restrict__ b1, unsigned short* __restrict__ hbh) {
    const int tid = threadIdx.x;
    const int wave = tid >> 6, lane = tid & 63;
    const int quad = lane >> 4, l15 = lane & 15;
    const int b0 = blockIdx.x * 16;
    const int nt = blockIdx.y * 4 + wave;
    if (nt >= 50) return;                  // wave-uniform
    const unsigned short* arow = xbh + (size_t)(b0 + l15) * KP + quad * 8;
    f32x4 acc = {0.f, 0.f, 0.f, 0.f};
    #pragma unroll
    for (int kt = 0; kt < 10; ++kt) {
        bf16x8 a = *(const bf16x8*)(arow + kt * 32);
        bf16x8 bv = *(const bf16x8*)(w1frag + ((size_t)(nt * 10 + kt) * 64 + lane) * 8);
        acc = __builtin_amdgcn_mfma_f32_16x16x32_bf16(a, bv, acc, 0, 0, 0);
    }
    const int col = nt * 16 + l15;
    const float bias = b1[col];
    #pragma unroll
    for (int r = 0; r < 4; ++r) {
        int row = b0 + quad * 4 + r;
        hbh[(size_t)row * Hn + col] = f2bf(fmaxf(acc[r] + bias, 0.f));
    }
}

// mu/lv via MFMA -> LDS (stride 65) -> per-wave softmax/theta/kl epilogue.
__global__ __launch_bounds__(256) void k3_theta(
        const unsigned short* __restrict__ hbh,
        const unsigned short* __restrict__ wfrag,
        const float* __restrict__ bmu, const float* __restrict__ blv,
        float* __restrict__ theta, float* __restrict__ loss) {
    __shared__ float mlds[16 * 65];
    __shared__ float llds[16 * 65];
    const int tid = threadIdx.x;
    const int wave = tid >> 6, lane = tid & 63;
    const int quad = lane >> 4, l15 = lane & 15;
    const int b0 = blockIdx.x * 16;
    const unsigned short* arow = hbh + (size_t)(b0 + l15) * Hn + quad * 8;
    f32x4 am = {0.f, 0.f, 0.f, 0.f}, al = {0.f, 0.f, 0.f, 0.f};
    #pragma unroll
    for (int kt = 0; kt < 25; ++kt) {
        bf16x8 a  = *(const bf16x8*)(arow + kt * 32);
        bf16x8 bm = *(const bf16x8*)(wfrag + ((size_t)(wave * 25 + kt) * 64 + lane) * 8);
        bf16x8 bl = *(const bf16x8*)(wfrag + ((size_t)((4 + wave) * 25 + kt) * 64 + lane) * 8);
        am = __builtin_amdgcn_mfma_f32_16x16x32_bf16(a, bm, am, 0, 0, 0);
        al = __builtin_amdgcn_mfma_f32_16x16x32_bf16(a, bl, al, 0, 0, 0);
    }
    const int t = wave * 16 + l15;                 // 0..63 LDS col
    const float bm_ = (t < Tn) ? bmu[t] : 0.f;
    const float bl_ = (t < Tn) ? blv[t] : 0.f;
    #pragma unroll
    for (int r = 0; r < 4; ++r) {
        int row = quad * 4 + r;
        mlds[row * 65 + t] = am[r] + bm_;
        llds[row * 65 + t] = al[r] + bl_;
    }
    __syncthreads();
    const int tt = (lane < Tn) ? lane : (Tn - 1);
    const bool act = (lane < Tn);
    float klacc = 0.f;
    #pragma unroll
    for (int k = 0; k < 4; ++k) {
        int row = wave * 4 + k;
        float mu = mlds[row * 65 + tt];
        float lv = llds[row * 65 + tt];
        float m = waveReduceMax(act ? mu : -1e30f);
        float ex = act ? expf(mu - m) : 0.f;
        float ssum = waveReduceSum(ex);
        if (act) theta[(b0 + row) * Tn + lane] = ex / ssum;
        klacc += waveReduceSum(act ? (1.f + lv - mu * mu - expf(lv)) : 0.f);
    }
    if (lane == 0) atomicAdd(loss, -0.5f * klacc * (1.0f / (float)Bn));
}

// recon[b] = -sum_tok log( sum_t (theta/Z)[t] * betaU[tok,t] + 1e-5 ).
__global__ __launch_bounds__(256) void k6_recon(
        const int* __restrict__ toks, const int* __restrict__ cnt,
        const float* __restrict__ theta, const float* __restrict__ topicsum,
        const unsigned short* __restrict__ betaUh, float* __restrict__ loss) {
    __shared__ float sw[Tn];
    __shared__ float swred[4];
    const int b = blockIdx.x, tid = threadIdx.x;
    if (tid < Tn) sw[tid] = theta[b * Tn + tid] / topicsum[tid];
    __syncthreads();
    float wr[Tn];
    #pragma unroll
    for (int t = 0; t < Tn; ++t) wr[t] = sw[t];
    float lsum = 0.f;
    const int n = cnt[b];
    for (int i = tid; i < n; i += 256) {
        int v = toks[b * Sn + i];
        const uint4* q = (const uint4*)(betaUh + (size_t)v * BSTR);
        float dot = 0.f;
        #pragma unroll
        for (int k = 0; k < 6; ++k) {
            uint4 u = q[k];
            int t = 8 * k;
            dot += wr[t]     * bf_lo(u.x) + wr[t + 1] * bf_hi(u.x);
            dot += wr[t + 2] * bf_lo(u.y) + wr[t + 3] * bf_hi(u.y);
            dot += wr[t + 4] * bf_lo(u.z) + wr[t + 5] * bf_hi(u.z);
            dot += wr[t + 6] * bf_lo(u.w) + wr[t + 7] * bf_hi(u.w);
        }
        unsigned d = ((const unsigned*)q)[24];
        dot += wr[48] * bf_lo(d) + wr[49] * bf_hi(d);
        lsum += logf(dot + 1e-5f);
    }
    float s = waveReduceSum(lsum);
    const int wave = tid >> 6, lane = tid & 63;
    if (lane == 0) swred[wave] = s;
    __syncthreads();
    if (tid == 0) {
        float tot = swred[0] + swred[1] + swred[2] + swred[3];
        atomicAdd(loss, -tot * (1.0f / (float)Bn));
    }
}

extern "C" void kernel_launch(void* const* d_in, const int* in_sizes, int n_in,
                              void* d_out, int out_size, void* d_ws, size_t ws_size,
                              hipStream_t stream) {
    const int*   ids   = (const int*)d_in[0];
    const float* rho   = (const float*)d_in[1];
    const float* alpha = (const float*)d_in[2];
    const float* W1    = (const float*)d_in[3];
    const float* b1    = (const float*)d_in[4];
    const float* Wmu   = (const float*)d_in[5];
    const float* bmu   = (const float*)d_in[6];
    const float* Wlv   = (const float*)d_in[7];
    const float* blv   = (const float*)d_in[8];

    float* theta = (float*)d_out;            // [B, T]
    float* loss  = theta + Bn * Tn;          // scalar at d_out[51200]

    const int k4grid = (Vn + 63) / 64;                  // 782
    char* w = (char*)d_ws;
    float* topicsum = (float*)w;                w += 256;
    unsigned short* bfrag = (unsigned short*)w; w += 4 * 10 * 64 * 8 * 2;
    unsigned short* w1frag = (unsigned short*)w; w += (size_t)W1FRAG_N * 2;
    unsigned short* wfrag = (unsigned short*)w;  w += (size_t)WFRAG_N * 2;
    int*   cnt      = (int*)w;                  w += Bn * 4;
    int*   toks     = (int*)w;                  w += Bn * Sn * 4;
    float* xbar     = (float*)w;                w += Bn * En * 4;
    unsigned short* xbh = (unsigned short*)w;   w += (size_t)Bn * KP * 2;
    unsigned short* hbh = (unsigned short*)w;   w += (size_t)Bn * Hn * 2;
    unsigned short* rhoh = (unsigned short*)w;  w += (size_t)Vn * KP * 2;   // 32 MB
    unsigned int* betaU32 = (unsigned int*)w;   w += (size_t)k4grid * 64 * 128;

    k0_init<<<(Bn * En + 255) / 256, 256, 0, stream>>>(alpha, bfrag, topicsum, loss, xbar);
    kp_prep<<<(W1FRAG_N + WFRAG_N + 255) / 256, 256, 0, stream>>>(
        W1, Wmu, Wlv, w1frag, wfrag);
    k5_cast<<<(Vn * (KP / 4) + 255) / 256, 256, 0, stream>>>(
        (const float4*)rho, (ushort4*)rhoh);
    k4_beta<<<k4grid, 256, 0, stream>>>(rhoh, bfrag, betaU32, topicsum);
    k1_tokens_x<<<Bn * NRANGE, 256, 0, stream>>>(ids, (const unsigned int*)rhoh,
                                                 toks, cnt, xbar);
    k2a_xcast<<<(Bn * KP + 255) / 256, 256, 0, stream>>>(xbar, cnt, xbh);
    k2_h<<<dim3(64, 13), 256, 0, stream>>>(xbh, w1frag, b1, hbh);
    k3_theta<<<64, 256, 0, stream>>>(hbh, wfrag, bmu, blv, theta, loss);
    k6_recon<<<Bn, 256, 0, stream>>>(toks, cnt, theta, topicsum,
                                     (const unsigned short*)betaU32, loss);
}